// Round 10
// baseline (112.211 us; speedup 1.0000x reference)
//
#include <hip/hip_runtime.h>
#include <math.h>

#define TPB 512           // 8 waves/block
#define CH  32            // samples per chunk
#define CPB 8             // chunks per block

static constexpr int B_     = 64;
static constexpr int S_     = 2048;
static constexpr int TOTAL  = B_ * S_;          // 131072 samples
static constexpr int NCHUNK = TOTAL / CH;       // 4096
static constexpr int NBLK   = NCHUNK / CPB;     // 512 blocks = 2/CU exactly
static constexpr int SAMPB  = 600;              // bytes per sample (150 f32)
static constexpr int PREDB  = (CH + 2) * SAMPB; // 20400 B pred incl. 2-sample halo
static constexpr int TGTB   = CH * SAMPB;       // 19200 B tgt
static constexpr int CHB    = PREDB + TGTB;     // 39600 B staged per chunk
static constexpr int NSLICE = 39;               // ceil(CHB/1024)
static constexpr int BUFB   = NSLICE * 1024;    // 39936; 2 bufs = 79872 B (2 blocks/CU)
static constexpr long TOTB  = (long)TOTAL * SAMPB;

// ---- 26 chain tasks A-B-C == edges (A,B),(B,C); covers the 51-edge union
// (bone-49 + conn-49, 47 shared) exactly once. Task 25 = single edge (4,8),
// second edge (8,8) has zero length and sentinel params -> contributes 0.
__constant__ int CA_[26] = {0,2,1,6,7,  8,10,8,14,8,18,8,22,8,26,  29,31,29,35,29,39,29,43,29,47, 4};
__constant__ int CB_[26] = {1,3,5,7,29, 9,11,13,15,17,19,21,23,25,27, 30,32,34,36,38,40,42,44,46,48, 8};
__constant__ int CC_[26] = {2,4,6,8,4,  10,12,14,16,18,20,22,24,26,28, 31,33,35,37,39,41,43,45,47,49, 8};
__constant__ int SL_[24] = {8,9,10,11,12,13,14,15,16,17,18,19,20,21,22,23,24,25,26,27,28,2,3,4};
__constant__ int SR_[24] = {29,30,31,32,33,34,35,36,37,38,39,40,41,42,43,44,45,46,47,48,49,5,6,7};
__constant__ int AJ_[4] = {1,1,2,5};
__constant__ int BJ_[4] = {2,5,3,6};
__constant__ int CJ_[4] = {3,6,4,7};

struct F3 { float x, y, z; };
__device__ __forceinline__ F3 ld3(const float* p) { return *(const F3*)p; }
#define SQRTF __builtin_amdgcn_sqrtf

typedef const __attribute__((address_space(1))) void* gas_t;
typedef __attribute__((address_space(3))) void* las_t;

__global__ __launch_bounds__(TPB, 4) void pose_main(
    const float* __restrict__ pred, const float* __restrict__ tgt,
    float* __restrict__ part, int* __restrict__ cnt, float* __restrict__ out)
{
    __shared__ __align__(16) char LDS[2 * BUFB];   // 79872 B -> 2 blocks/CU
    __shared__ int lastflag;

    const int tid = threadIdx.x;
    const int blk = blockIdx.x;
    const int li  = tid & 15;        // 16-lane sample groups (conflict-free banking)
    const int g   = tid >> 4;        // task group 0..31

    // ========== hoisted per-thread constants ==========
    // chain task (g<26): joints A,B,C + per-edge params
    const int gg  = (g < 26) ? g : 0;
    const int cAo = CA_[gg] * 3, cBo = CB_[gg] * 3, cCo = CC_[gg] * 3;
    float mn1 = 0.01f, mx1 = 0.08f, w1 = 1.f;     // hand default
    float mn2 = 0.01f, mx2 = 0.08f, w2 = 1.f;
    if      (g == 0)  { mn1=0.05f; mx1=0.15f;        mn2=0.1f;  mx2=0.2f;  }
    else if (g == 1)  { mn1=0.2f;  mx1=0.35f;        mn2=0.2f;  mx2=0.35f; }
    else if (g == 2)  { mn1=0.1f;  mx1=0.2f;         mn2=0.2f;  mx2=0.35f; }
    else if (g == 3)  { mn1=0.2f;  mx1=0.35f;        mn2=-1e9f; mx2=1e9f;  }
    else if (g == 4)  { mn1=0.05f; mx1=0.15f; w1=0.f; mn2=-1e9f; mx2=1e9f; }
    else if (g == 25) { mn1=0.05f; mx1=0.15f; w1=0.f; mn2=-1e9f; mx2=1e9f; w2=0.f; }
    // symmetry: k=g for g<24
    const bool sy_on = (g < 24);
    const int  ksy = sy_on ? g : 0;
    const int  syL = SL_[ksy] * 3, syR = SR_[ksy] * 3;
    // angle: k=g for g<4
    const int aAo = AJ_[g & 3] * 3, aBo = BJ_[g & 3] * 3, aCo2 = CJ_[g & 3] * 3;
    // temporal: thread t<400 owns joint j=t%50, sample-run r=t/50 (4 samples)
    const bool tp_on = (tid < 400);
    const int  jq  = tid % 50;
    const int  rq  = tid / 50;
    const int  tbase = (rq * 4) * 150 + jq * 3;    // dword offset of (run-start, joint)
    const int  ss  = rq * 4;

    float a_bone = 0.f, a_ang = 0.f, a_sym = 0.f, a_vel = 0.f, a_acc = 0.f, a_sup = 0.f;

    // ============ async HBM->LDS staging: 39 wave-slices of 1024 B ============
    const int w      = tid >> 6;
    const int lane16 = (tid & 63) << 4;
    auto stage = [&](int cidx, char* lbuf) {
        const long nb = (long)cidx * TGTB;
        const char* pb = (const char*)pred + nb;
        const char* tb = (const char*)tgt  + nb - PREDB;
        const long prem = TOTB - nb - 16;        // clamp pred halo at buffer end
        #pragma unroll
        for (int s = 0; s < 5; ++s) {
            const int slice = w + s * 8;
            if (slice < NSLICE) {                // wave-uniform
                const long o = (long)slice * 1024 + lane16;
                const char* src = (o < PREDB)
                    ? pb + (o > prem ? prem : o)
                    : tb + (o > (long)(CHB - 16) ? (long)(CHB - 16) : o);
                __builtin_amdgcn_global_load_lds((gas_t)src, (las_t)(lbuf + slice * 1024), 16, 0, 0);
            }
        }
    };

    const int c0 = blk * CPB;
    stage(c0, LDS);                  // prologue: chunk 0 -> buf0

    #pragma unroll 2
    for (int c = 0; c < CPB; ++c) {
        char* curb = LDS + (c & 1) * BUFB;
        char* nxtb = LDS + ((c & 1) ^ 1) * BUFB;
        if (c + 1 < CPB) {
            stage(c0 + c + 1, nxtb);             // prefetch next chunk
            if (w < 7) asm volatile("s_waitcnt vmcnt(5)" ::: "memory");
            else       asm volatile("s_waitcnt vmcnt(4)" ::: "memory");
        } else {
            asm volatile("s_waitcnt vmcnt(0)" ::: "memory");
        }
        __builtin_amdgcn_s_barrier();            // everyone's cur loads landed
        __builtin_amdgcn_sched_barrier(0);       // no ds_read hoisted above this

        const float* Jl = (const float*)curb;
        const float* Tl = Jl + PREDB / 4;
        const int s_base = ((c0 + c) * CH) & (S_ - 1);

        // ---------- per-sample tasks (samples li and li+16) ----------
        #pragma unroll
        for (int h = 0; h < 2; ++h) {
            const int sb = (li + h * 16) * 150;
            const float* Jp = Jl + sb;
            const float* Tp = Tl + sb;

            // chain task: 2 edges, 6 ld3 (middle endpoint shared)
            if (g < 26) {
                const F3 jA = ld3(Jp + cAo), jB = ld3(Jp + cBo), jC = ld3(Jp + cCo);
                float dx = jA.x - jB.x, dy = jA.y - jB.y, dz = jA.z - jB.z;
                const float len1 = SQRTF(dx*dx + dy*dy + dz*dz);
                dx = jB.x - jC.x; dy = jB.y - jC.y; dz = jB.z - jC.z;
                const float len2 = SQRTF(dx*dx + dy*dy + dz*dz);
                a_bone += fmaxf(len1 - mx1, 0.f) + fmaxf(mn1 - len1, 0.f)
                        + fmaxf(len2 - mx2, 0.f) + fmaxf(mn2 - len2, 0.f);
                const F3 tA = ld3(Tp + cAo), tB = ld3(Tp + cBo), tC = ld3(Tp + cCo);
                dx = tA.x - tB.x; dy = tA.y - tB.y; dz = tA.z - tB.z;
                const float tl1 = SQRTF(dx*dx + dy*dy + dz*dz);
                dx = tB.x - tC.x; dy = tB.y - tC.y; dz = tB.z - tC.z;
                const float tl2 = SQRTF(dx*dx + dy*dy + dz*dz);
                a_sup += w1 * fabsf(len1 - tl1) + w2 * fabsf(len2 - tl2);
            }

            // symmetry
            if (sy_on) {
                const F3 L = ld3(Jp + syL), R = ld3(Jp + syR);
                a_sym += fabsf(L.x + R.x) + 0.5f * (fabsf(L.y - R.y) + fabsf(L.z - R.z));
            }

            // angles (g<4)
            if (g < 4) {
                const F3 A = ld3(Jp + aAo), Bb = ld3(Jp + aBo), C = ld3(Jp + aCo2);
                const float v1x = A.x - Bb.x, v1y = A.y - Bb.y, v1z = A.z - Bb.z;
                const float v2x = C.x - Bb.x, v2y = C.y - Bb.y, v2z = C.z - Bb.z;
                const float n12 = (v1x*v1x + v1y*v1y + v1z*v1z) * (v2x*v2x + v2y*v2y + v2z*v2z);
                const float inv = __frsqrt_rn(fmaxf(n12, 1e-24f));
                float cosv = (v1x*v2x + v1y*v2y + v1z*v2z) * inv;
                cosv = fminf(fmaxf(cosv, -1.f), 1.f);
                const float deg = acosf(cosv) * 57.29577951308232f;
                a_ang += fmaxf(30.f - deg, 0.f) + fmaxf(deg - 150.f, 0.f);
            }
        }

        // ---------- temporal: joint jq, samples ss..ss+3 (6 reads, 4 vel+acc) ----------
        if (tp_on) {
            F3 q0 = ld3(Jl + tbase);
            F3 q1 = ld3(Jl + tbase + 150);
            F3 q2 = ld3(Jl + tbase + 300);
            F3 q3 = ld3(Jl + tbase + 450);
            F3 q4 = ld3(Jl + tbase + 600);
            F3 q5 = ld3(Jl + tbase + 750);
            const F3 qs[6] = {q0, q1, q2, q3, q4, q5};
            #pragma unroll
            for (int i = 0; i < 4; ++i) {
                const int sidx = s_base + ss + i;
                if (sidx < S_ - 1) {
                    const float vx = qs[i+1].x - qs[i].x;
                    const float vy = qs[i+1].y - qs[i].y;
                    const float vz = qs[i+1].z - qs[i].z;
                    a_vel += SQRTF(vx*vx + vy*vy + vz*vz);
                    if (sidx < S_ - 2) {
                        const float ax = qs[i+2].x - 2.f*qs[i+1].x + qs[i].x;
                        const float ay = qs[i+2].y - 2.f*qs[i+1].y + qs[i].y;
                        const float az = qs[i+2].z - 2.f*qs[i+1].z + qs[i].z;
                        a_acc += SQRTF(ax*ax + ay*ay + az*az);
                    }
                }
            }
        }

        asm volatile("" ::: "memory");   // block LDS-load CSE across chunk iterations
        __builtin_amdgcn_s_barrier();    // all done reading curb before it is restaged
    }

    // ================= block reduction =================
    float vals[6] = {a_bone, a_ang, a_sym, a_vel, a_acc, a_sup};
    #pragma unroll
    for (int k = 0; k < 6; ++k)
        #pragma unroll
        for (int off = 32; off > 0; off >>= 1)
            vals[k] += __shfl_down(vals[k], off, 64);

    float* red = (float*)LDS;            // reuse staging LDS (final barrier passed)
    const int lane = tid & 63;
    if (lane == 0) {
        #pragma unroll
        for (int k = 0; k < 6; ++k) red[w * 6 + k] = vals[k];
    }
    __syncthreads();
    if (tid == 0) {
        #pragma unroll
        for (int k = 0; k < 6; ++k) {    // SoA partials: part[k][blk]
            float s = 0.f;
            #pragma unroll
            for (int v = 0; v < 8; ++v) s += red[v * 6 + k];
            part[k * NBLK + blk] = s;
        }
    }

    // ================= last-block finalize (fused pose_reduce) =================
    __threadfence();                     // release partials (device scope)
    if (tid == 0) lastflag = (atomicAdd(cnt, 1) == NBLK - 1) ? 1 : 0;
    __syncthreads();
    if (lastflag) {
        __threadfence();                 // acquire all blocks' partials
        const int k = tid >> 6;          // wave k sums component k
        float s = 0.f;
        if (k < 6) {
            volatile const float* vp = part + k * NBLK;
            #pragma unroll
            for (int m = 0; m < NBLK; m += 64) s += vp[m + lane];
            #pragma unroll
            for (int off = 32; off > 0; off >>= 1) s += __shfl_down(s, off, 64);
            if (lane == 0) red[64 + k] = s;
        }
        __syncthreads();
        if (tid == 0) {
            const float bone = red[64] * (1.f / ((float)TOTAL * 49.f));
            const float ang  = red[65] * (1.f / ((float)TOTAL * 4.f));
            const float sym  = red[66] * (1.f / ((float)TOTAL * 24.f));
            const float temporal = red[68] * (1.f / ((float)B_ * (float)(S_ - 2) * 50.f))
                                 + 0.5f * red[67] * (1.f / ((float)B_ * (float)(S_ - 1) * 50.f));
            const float sup  = red[69] * (1.f / ((float)TOTAL * 49.f));
            out[0] = bone;
            out[1] = ang;
            out[2] = sym;
            out[3] = temporal;
            out[4] = sup;
            out[5] = bone + 0.5f * ang + 0.3f * sym + 0.2f * temporal + sup;
        }
    }
}

extern "C" void kernel_launch(void* const* d_in, const int* in_sizes, int n_in,
                              void* d_out, int out_size, void* d_ws, size_t ws_size,
                              hipStream_t stream)
{
    const float* pred = (const float*)d_in[0];
    const float* tgt  = (const float*)d_in[1];
    float* part = (float*)d_ws;                          // 6*512 f32 = 12288 B (SoA)
    int*   cnt  = (int*)((char*)d_ws + 6 * NBLK * 4);    // arrival counter
    hipMemsetAsync(cnt, 0, 4, stream);                   // graph-capturable
    pose_main<<<NBLK, TPB, 0, stream>>>(pred, tgt, part, cnt, (float*)d_out);
}

// Round 11
// 37.538 us; speedup vs baseline: 2.9892x; 2.9892x over previous
//
#include <hip/hip_runtime.h>
#include <math.h>

#define TPB 1024          // 16 waves/block
#define CH  64            // samples per chunk
#define CPB 8             // chunks per block

static constexpr int B_     = 64;
static constexpr int S_     = 2048;
static constexpr int TOTAL  = B_ * S_;          // 131072 samples
static constexpr int NCHUNK = TOTAL / CH;       // 2048
static constexpr int NBLK   = NCHUNK / CPB;     // 256 blocks = 1/CU exactly
static constexpr int SAMPB  = 600;              // bytes per sample (150 f32)
static constexpr int PREDB  = (CH + 2) * SAMPB; // 39600 B pred incl. 2-sample halo
static constexpr int TGTB   = CH * SAMPB;       // 38400 B tgt
static constexpr int CHB    = PREDB + TGTB;     // 78000 B staged per chunk
static constexpr int NSLICE = 77;               // ceil(CHB/1024)
static constexpr int BUFB   = NSLICE * 1024;    // 78848; 2 bufs = 157696 B (1 block/CU)
static constexpr long TOTB  = (long)TOTAL * SAMPB;

// ---- union bone table: 51 edges covers bone-set(49) + conn-set(49) ----
// k=9,10 conn-only -> sentinel ranges; k=7,8 bone-only -> wsup=0.
// k>=11 (hand edges): min=0.01, max=0.08, wsup=1 (compile-time constants).
__constant__ int US_[51] = {0,1,1,2,3,5,6,4,7,7,4,
    8,8,8,8,8,9,10,11,13,14,
    15,17,18,19,21,22,23,25,26,27,
    29,29,29,29,29,30,31,32,34,35,
    36,38,39,40,42,43,44,46,47,48};
__constant__ int UE_[51] = {1,2,5,3,4,6,7,8,29,8,29,
    9,13,17,21,25,10,11,12,14,15,
    16,18,19,20,22,23,24,26,27,28,
    30,34,38,42,46,31,32,33,35,36,
    37,39,40,41,43,44,45,47,48,49};
__constant__ float UMIN11_[11] = {0.05f,0.1f,0.1f,0.2f,0.2f,0.2f,0.2f,0.05f,0.05f,-1e9f,-1e9f};
__constant__ float UMAX11_[11] = {0.15f,0.2f,0.2f,0.35f,0.35f,0.35f,0.35f,0.15f,0.15f,1e9f,1e9f};
__constant__ float WSUP11_[11] = {1.f,1.f,1.f,1.f,1.f,1.f,1.f,0.f,0.f,1.f,1.f};
__constant__ int SL_[24] = {8,9,10,11,12,13,14,15,16,17,18,19,20,21,22,23,24,25,26,27,28,2,3,4};
__constant__ int SR_[24] = {29,30,31,32,33,34,35,36,37,38,39,40,41,42,43,44,45,46,47,48,49,5,6,7};
__constant__ int AJ_[4] = {1,1,2,5};
__constant__ int BJ_[4] = {2,5,3,6};
__constant__ int CJ_[4] = {3,6,4,7};

struct F3 { float x, y, z; };
__device__ __forceinline__ F3 ld3(const float* p) { return *(const F3*)p; }
#define SQRTF __builtin_amdgcn_sqrtf

typedef const __attribute__((address_space(1))) void* gas_t;
typedef __attribute__((address_space(3))) void* las_t;

__global__ __launch_bounds__(TPB, 4) void pose_main(
    const float* __restrict__ pred, const float* __restrict__ tgt,
    float* __restrict__ part)
{
    __shared__ __align__(16) char LDS[2 * BUFB];   // 157696 B -> 1 block/CU (16 waves)

    const int tid = threadIdx.x;
    const int blk = blockIdx.x;
    const int li  = tid & 15;        // 16-lane sample groups (proven conflict-light)
    const int g   = tid >> 4;        // task group 0..63
    // each thread handles samples li, li+16, li+32, li+48 of the chunk

    // ========== hoisted per-thread constants (joint offsets, floats) ==========
    // union: edge k=g for g<51 (one edge per group)
    const bool u_on = (g < 51);
    const int  gu   = u_on ? g : 0;
    const int  uOs = US_[gu] * 3, uOe = UE_[gu] * 3;
    const float uMn = (gu < 11) ? UMIN11_[gu] : 0.01f;
    const float uMx = (gu < 11) ? UMAX11_[gu] : 0.08f;
    const float uW  = (gu < 11) ? WSUP11_[gu] : 1.f;
    // symmetry: k=g for g<24
    const bool sy_on = (g < 24);
    const int  ksy = sy_on ? g : 0;
    const int  syL = SL_[ksy] * 3, syR = SR_[ksy] * 3;
    // angle: on groups g=60..63 (otherwise-idle wave 15), k=g-60
    const bool an_on = (g >= 60);
    const int  ka  = (g - 60) & 3;
    const int  aAo = AJ_[ka] * 3, aBo = BJ_[ka] * 3, aCo = CJ_[ka] * 3;
    // temporal: joint j=g for g<50
    const bool t_on = (g < 50);
    const int  tO0 = g * 3;

    float a_bone = 0.f, a_ang = 0.f, a_sym = 0.f, a_vel = 0.f, a_acc = 0.f, a_sup = 0.f;

    // ============ async HBM->LDS staging: 77 wave-slices of 1024 B ============
    // wave w stages slices {w+16s | s<5, w+16s<77}; waves 0-12: 5 loads, 13-15: 4.
    const int w      = tid >> 6;
    const int lane16 = (tid & 63) << 4;
    auto stage = [&](int cidx, char* lbuf) {
        const long nb = (long)cidx * TGTB;
        const char* pb = (const char*)pred + nb;
        const char* tb = (const char*)tgt  + nb - PREDB;
        const long prem = TOTB - nb - 16;        // clamp pred halo at buffer end
        #pragma unroll
        for (int s = 0; s < 5; ++s) {
            const int slice = w + s * 16;
            if (slice < NSLICE) {                // wave-uniform
                const long o = (long)slice * 1024 + lane16;
                const char* src = (o < PREDB)
                    ? pb + (o > prem ? prem : o)
                    : tb + (o > (long)(CHB - 16) ? (long)(CHB - 16) : o);
                __builtin_amdgcn_global_load_lds((gas_t)src, (las_t)(lbuf + slice * 1024), 16, 0, 0);
            }
        }
    };

    const int c0 = blk * CPB;
    stage(c0, LDS);                  // prologue: chunk 0 -> buf0

    #pragma unroll
    for (int c = 0; c < CPB; ++c) {
        char* curb = LDS + (c & 1) * BUFB;
        char* nxtb = LDS + ((c & 1) ^ 1) * BUFB;
        if (c + 1 < CPB) {
            stage(c0 + c + 1, nxtb);             // prefetch next chunk
            if (w < 13) asm volatile("s_waitcnt vmcnt(5)" ::: "memory");
            else        asm volatile("s_waitcnt vmcnt(4)" ::: "memory");
        } else {
            asm volatile("s_waitcnt vmcnt(0)" ::: "memory");
        }
        __builtin_amdgcn_s_barrier();            // everyone's cur loads landed
        __builtin_amdgcn_sched_barrier(0);       // no ds_read hoisted above this

        const float* Jl = (const float*)curb;
        const float* Tl = Jl + PREDB / 4;
        const int s_base = ((c0 + c) * CH) & (S_ - 1);

        #pragma unroll
        for (int h = 0; h < 4; ++h) {
            const int sb = (li + h * 16) * 150;
            const float* Jp = Jl + sb;
            const float* Tp = Tl + sb;

            // ---------- union: bone penalty + supervised (g<51) ----------
            if (u_on) {
                const F3 je = ld3(Jp + uOe), js = ld3(Jp + uOs);
                const float dx = je.x - js.x, dy = je.y - js.y, dz = je.z - js.z;
                const float pb = SQRTF(dx * dx + dy * dy + dz * dz);
                a_bone += fmaxf(pb - uMx, 0.f) + fmaxf(uMn - pb, 0.f);
                const F3 te = ld3(Tp + uOe), ts = ld3(Tp + uOs);
                const float tx = te.x - ts.x, ty = te.y - ts.y, tz = te.z - ts.z;
                const float tb = SQRTF(tx * tx + ty * ty + tz * tz);
                a_sup += uW * fabsf(pb - tb);
            }

            // ---------- symmetry (g<24) ----------
            if (sy_on) {
                const F3 L = ld3(Jp + syL), R = ld3(Jp + syR);
                a_sym += fabsf(L.x + R.x) + 0.5f * (fabsf(L.y - R.y) + fabsf(L.z - R.z));
            }

            // ---------- angles (g=60..63) ----------
            if (an_on) {
                const F3 A = ld3(Jp + aAo), Bb = ld3(Jp + aBo), C = ld3(Jp + aCo);
                const float v1x = A.x - Bb.x, v1y = A.y - Bb.y, v1z = A.z - Bb.z;
                const float v2x = C.x - Bb.x, v2y = C.y - Bb.y, v2z = C.z - Bb.z;
                const float n12 = (v1x*v1x + v1y*v1y + v1z*v1z) * (v2x*v2x + v2y*v2y + v2z*v2z);
                const float inv = __frsqrt_rn(fmaxf(n12, 1e-24f));
                float cosv = (v1x*v2x + v1y*v2y + v1z*v2z) * inv;
                cosv = fminf(fmaxf(cosv, -1.f), 1.f);
                const float deg = acosf(cosv) * 57.29577951308232f;
                a_ang += fmaxf(30.f - deg, 0.f) + fmaxf(deg - 150.f, 0.f);
            }

            // ---------- temporal (g<50): joint g, sample li+h*16 ----------
            if (t_on) {
                const int sidx = s_base + li + h * 16;
                const bool v_ok = sidx < S_ - 1;
                const bool a_ok = sidx < S_ - 2;
                const F3 p0 = ld3(Jp + tO0), p1 = ld3(Jp + tO0 + 150), p2 = ld3(Jp + tO0 + 300);
                if (v_ok) {
                    const float vx = p1.x - p0.x, vy = p1.y - p0.y, vz = p1.z - p0.z;
                    a_vel += SQRTF(vx*vx + vy*vy + vz*vz);
                    if (a_ok) {
                        const float ax = p2.x - 2.f*p1.x + p0.x;
                        const float ay = p2.y - 2.f*p1.y + p0.y;
                        const float az = p2.z - 2.f*p1.z + p0.z;
                        a_acc += SQRTF(ax*ax + ay*ay + az*az);
                    }
                }
            }
        }

        asm volatile("" ::: "memory");   // block LDS-load CSE across chunk iterations
        __builtin_amdgcn_s_barrier();    // all done reading curb before it is restaged
    }

    // ================= block reduction =================
    float vals[6] = {a_bone, a_ang, a_sym, a_vel, a_acc, a_sup};
    #pragma unroll
    for (int k = 0; k < 6; ++k)
        #pragma unroll
        for (int off = 32; off > 0; off >>= 1)
            vals[k] += __shfl_down(vals[k], off, 64);

    float* red = (float*)LDS;            // reuse staging LDS (final barrier passed)
    const int lane = tid & 63;
    if (lane == 0) {
        #pragma unroll
        for (int k = 0; k < 6; ++k) red[w * 6 + k] = vals[k];
    }
    __syncthreads();
    if (tid == 0) {
        #pragma unroll
        for (int k = 0; k < 6; ++k) {    // SoA partials: part[k][blk]
            float s = 0.f;
            #pragma unroll
            for (int v = 0; v < 16; ++v) s += red[v * 6 + k];
            part[k * NBLK + blk] = s;
        }
    }
}

__global__ __launch_bounds__(256) void pose_reduce(
    const float* __restrict__ part, float* __restrict__ out)
{
    __shared__ float red[4][6];
    const int tid = threadIdx.x;
    float a[6];
    #pragma unroll
    for (int k = 0; k < 6; ++k) {
        float s = 0.f;
        for (int i = tid; i < NBLK; i += 256) s += part[k * NBLK + i];
        a[k] = s;
    }
    #pragma unroll
    for (int k = 0; k < 6; ++k)
        #pragma unroll
        for (int off = 32; off > 0; off >>= 1)
            a[k] += __shfl_down(a[k], off, 64);

    const int wid = tid >> 6, lane = tid & 63;
    if (lane == 0) {
        #pragma unroll
        for (int k = 0; k < 6; ++k) red[wid][k] = a[k];
    }
    __syncthreads();
    if (tid == 0) {
        float t[6];
        #pragma unroll
        for (int k = 0; k < 6; ++k) t[k] = red[0][k] + red[1][k] + red[2][k] + red[3][k];
        const float bone = t[0] * (1.f / ((float)TOTAL * 49.f));
        const float ang  = t[1] * (1.f / ((float)TOTAL * 4.f));
        const float sym  = t[2] * (1.f / ((float)TOTAL * 24.f));
        const float temporal = t[4] * (1.f / ((float)B_ * (float)(S_ - 2) * 50.f))
                             + 0.5f * t[3] * (1.f / ((float)B_ * (float)(S_ - 1) * 50.f));
        const float sup  = t[5] * (1.f / ((float)TOTAL * 49.f));
        out[0] = bone;
        out[1] = ang;
        out[2] = sym;
        out[3] = temporal;
        out[4] = sup;
        out[5] = bone + 0.5f * ang + 0.3f * sym + 0.2f * temporal + sup;
    }
}

extern "C" void kernel_launch(void* const* d_in, const int* in_sizes, int n_in,
                              void* d_out, int out_size, void* d_ws, size_t ws_size,
                              hipStream_t stream)
{
    const float* pred = (const float*)d_in[0];
    const float* tgt  = (const float*)d_in[1];
    float* part = (float*)d_ws;   // 6 * 256 f32 = 6 KB (SoA)
    pose_main<<<NBLK, TPB, 0, stream>>>(pred, tgt, part);
    pose_reduce<<<1, 256, 0, stream>>>(part, (float*)d_out);
}